// Round 1
// baseline (1553.349 us; speedup 1.0000x reference)
//
#include <hip/hip_runtime.h>
#include <hip/hip_bf16.h>

// Problem constants (fixed by the reference)
// N=128, C=64, T=256, V=25, S=3, RED=4, KER=25, PAD=12
#define NB   128
#define CH   64
#define TT   256
#define VV   25
#define TW   4          // t-tile per block in main kernel
// strides
#define X_N  409600     // 64*256*25
#define X_C  6400       // 256*25

// ---------------- workspace layout (floats) ----------------
// p     : 128*64*25 = 204800   (zeroed each call)
// gate  : 204800
// Af    : 1875
// wd2t  : 12288  ([s][c][o], BN scale folded)
// bias2 : 64
#define WS_P     0
#define WS_GATE  204800
#define WS_AF    409600
#define WS_WD2T  411520
#define WS_B2    423808

// ---------------- prep: tiny precompute --------------------
__global__ __launch_bounds__(256) void prep_kernel(
    const float* __restrict__ A, const float* __restrict__ PA,
    const float* __restrict__ wd, const float* __restrict__ bd,
    const float* __restrict__ gamma, const float* __restrict__ beta,
    const float* __restrict__ mean, const float* __restrict__ var,
    float* __restrict__ Af, float* __restrict__ wd2t, float* __restrict__ bias2)
{
    __shared__ float norms[75];
    __shared__ float scs[64];
    int tid = threadIdx.x;
    if (tid < 75) {
        int s = tid / 25, w = tid - s * 25;
        float acc = 0.f;
        for (int i = 0; i < 25; ++i) {
            float v = PA[s * 625 + i * 25 + w];
            acc += v * v;
        }
        norms[tid] = sqrtf(acc) + 1e-4f;   // L2 over dim=1 (rows), per column
    }
    if (tid < 64) {
        float sc = gamma[tid] * rsqrtf(var[tid] + 1e-5f);
        scs[tid] = sc;
        float bsum = bd[tid] + bd[64 + tid] + bd[128 + tid];
        bias2[tid] = bsum * sc + beta[tid] - mean[tid] * sc;
    }
    __syncthreads();
    for (int i = tid; i < 1875; i += 256) {
        int s = i / 625; int rem = i - s * 625; int w = rem % 25;
        Af[i] = A[i] + PA[i] / norms[s * 25 + w];
    }
    for (int i = tid; i < 12288; i += 256) {
        int s = i >> 12; int rem = i & 4095; int c = rem >> 6; int o = rem & 63;
        wd2t[i] = wd[s * 4096 + o * 64 + c] * scs[o];   // [s][c][o], scale folded
    }
}

// ---------------- main: einsum + BN + residual + ReLU + pool ----------------
// grid = 128 * 64 blocks (n, t-tile of 4), 256 threads (4 waves, lane=o)
__global__ __launch_bounds__(256) void main_kernel(
    const float* __restrict__ x, const float* __restrict__ Af,
    const float* __restrict__ wd2t, const float* __restrict__ bias2,
    float* __restrict__ yout, float* __restrict__ p)
{
    __shared__ float xs[6400];    // [c][t*25+v], row stride 100
    __shared__ float zsu[6400];   // union: zs[c][s*28+w] stride 84 (5376) | ysum[q][o*25+w] (6400)
    __shared__ float Afs[1875];
    __shared__ float b2s[64];

    int blk = blockIdx.x;
    int n = blk >> 6, tb = blk & 63;
    int t0 = tb * TW;
    int tid = threadIdx.x, lane = tid & 63, q = tid >> 6;

    for (int i = tid; i < 1875; i += 256) Afs[i] = Af[i];
    if (tid < 64) b2s[tid] = bias2[tid];

    const float* xn = x + (size_t)n * X_N;
    for (int i = tid; i < 6400; i += 256) {
        int c = i / 100; int r = i - c * 100;           // r = t*25+v
        xs[i] = xn[c * X_C + t0 * 25 + r];
    }
    // per-lane weights: wreg[s][j] = wd2t[s][q*16+j][lane]  (lane = output channel o)
    float wreg[3][16];
    #pragma unroll
    for (int s = 0; s < 3; ++s)
        #pragma unroll
        for (int j = 0; j < 16; ++j)
            wreg[s][j] = wd2t[(s * 64 + (q << 4) + j) * 64 + lane];
    __syncthreads();

    float pacc[7];
    #pragma unroll
    for (int ii = 0; ii < 7; ++ii) pacc[ii] = 0.f;

    for (int t = 0; t < TW; ++t) {
        // stage 1: z[c][s][w] = sum_v x[c][v] * Af[s][v][w]
        for (int i = tid; i < 4800; i += 256) {
            int c = i / 75; int sw = i - c * 75; int s = sw / 25; int w = sw - s * 25;
            const float* xr = &xs[c * 100 + t * 25];
            const float* ar = &Afs[s * 625 + w];
            float acc = 0.f;
            #pragma unroll
            for (int v = 0; v < 25; ++v) acc += xr[v] * ar[v * 25];
            zsu[c * 84 + s * 28 + w] = acc;
        }
        __syncthreads();
        // stage 2: lane = o; wave q covers c in [16q,16q+16); broadcast z reads
        float acc[25];
        #pragma unroll
        for (int w = 0; w < 25; ++w) acc[w] = 0.f;
        for (int s = 0; s < 3; ++s)
            for (int j = 0; j < 16; ++j) {
                int c = (q << 4) + j;
                float wt = wreg[s][j];
                const float* zr = &zsu[c * 84 + s * 28];
                #pragma unroll
                for (int w = 0; w < 25; ++w) acc[w] += zr[w] * wt;
            }
        __syncthreads();   // done reading zs; reuse as ysum
        #pragma unroll
        for (int w = 0; w < 25; ++w) zsu[q * 1600 + lane * 25 + w] = acc[w];
        __syncthreads();
        // reduce 4 wave-partials + bias + residual + relu; store; pool partial
        int ii = 0;
        for (int i = tid; i < 1600; i += 256, ++ii) {
            int o = i / 25; int w = i - o * 25;
            float r = b2s[o] + zsu[i] + zsu[1600 + i] + zsu[3200 + i] + zsu[4800 + i];
            r += xs[o * 100 + t * 25 + w];
            r = fmaxf(r, 0.f);
            yout[(size_t)n * X_N + o * X_C + (t0 + t) * 25 + w] = r;
            pacc[ii] += r;
        }
        __syncthreads();
    }
    int ii = 0;
    for (int i = tid; i < 1600; i += 256, ++ii)
        atomicAdd(&p[n * 1600 + i], pacc[ii]);
}

// ---------------- SCE gate ----------------
__global__ __launch_bounds__(256) void sce_kernel(
    const float* __restrict__ p, const float* __restrict__ sws,
    const float* __restrict__ sbs, const float* __restrict__ swe,
    const float* __restrict__ sbe, float* __restrict__ gate)
{
    __shared__ float pm[1600];
    __shared__ float wss[6400];
    __shared__ float sq[100];
    int n = blockIdx.x, tid = threadIdx.x;
    for (int i = tid; i < 1600; i += 256) pm[i] = p[n * 1600 + i] * (1.f / 256.f);
    for (int i = tid; i < 6400; i += 256) wss[i] = sws[i];
    __syncthreads();
    if (tid < 100) {
        int r = tid / 25, w = tid - (tid / 25) * 25;
        float acc = sbs[r];
        for (int o = 0; o < 64; ++o) {
            const float* wr = &wss[(r * 64 + o) * 25];
            const float* pr = &pm[o * 25];
            int k0 = (w < 12) ? 12 - w : 0;
            int k1 = (w > 12) ? 37 - w : 25;
            for (int k = k0; k < k1; ++k) acc += pr[w + k - 12] * wr[k];
        }
        sq[tid] = fmaxf(acc, 0.f);
    }
    __syncthreads();
    for (int i = tid; i < 1600; i += 256) {
        int o = i / 25, w = i - (i / 25) * 25;
        float acc = sbe[o];
        #pragma unroll
        for (int r = 0; r < 4; ++r) acc += sq[r * 25 + w] * swe[o * 4 + r];
        gate[n * 1600 + i] = 1.f + 1.f / (1.f + __expf(-acc));
    }
}

// ---------------- final gated multiply (in-place on d_out) ----------------
__global__ __launch_bounds__(256) void gate_mul_kernel(
    float* __restrict__ y, const float* __restrict__ gate)
{
    unsigned int i = (blockIdx.x * 256u + threadIdx.x) * 4u;   // < 52,428,800
    float4 v = *(float4*)(y + i);
    unsigned int i1 = i + 1, i2 = i + 2, i3 = i + 3;
    float g0 = gate[(i  / 6400u) * 25u + (i  % 25u)];
    float g1 = gate[(i1 / 6400u) * 25u + (i1 % 25u)];
    float g2 = gate[(i2 / 6400u) * 25u + (i2 % 25u)];
    float g3 = gate[(i3 / 6400u) * 25u + (i3 % 25u)];
    v.x *= g0; v.y *= g1; v.z *= g2; v.w *= g3;
    *(float4*)(y + i) = v;
}

extern "C" void kernel_launch(void* const* d_in, const int* in_sizes, int n_in,
                              void* d_out, int out_size, void* d_ws, size_t ws_size,
                              hipStream_t stream) {
    const float* x     = (const float*)d_in[0];
    const float* A     = (const float*)d_in[1];
    const float* PA    = (const float*)d_in[2];
    const float* wd    = (const float*)d_in[3];
    const float* bd    = (const float*)d_in[4];
    const float* gamma = (const float*)d_in[5];
    const float* beta  = (const float*)d_in[6];
    const float* mean  = (const float*)d_in[7];
    const float* var   = (const float*)d_in[8];
    const float* sws   = (const float*)d_in[9];
    const float* sbs   = (const float*)d_in[10];
    const float* swe   = (const float*)d_in[11];
    const float* sbe   = (const float*)d_in[12];

    float* out   = (float*)d_out;
    float* ws    = (float*)d_ws;
    float* p     = ws + WS_P;
    float* gate  = ws + WS_GATE;
    float* Af    = ws + WS_AF;
    float* wd2t  = ws + WS_WD2T;
    float* bias2 = ws + WS_B2;

    // p is accumulated with atomics; ws is poisoned 0xAA before every call
    hipMemsetAsync(p, 0, 204800 * sizeof(float), stream);

    prep_kernel<<<1, 256, 0, stream>>>(A, PA, wd, bd, gamma, beta, mean, var,
                                       Af, wd2t, bias2);
    main_kernel<<<NB * (TT / TW), 256, 0, stream>>>(x, Af, wd2t, bias2, out, p);
    sce_kernel<<<NB, 256, 0, stream>>>(p, sws, sbs, swe, sbe, gate);
    gate_mul_kernel<<<out_size / (256 * 4), 256, 0, stream>>>(out, gate);
}

// Round 2
// 786.374 us; speedup vs baseline: 1.9753x; 1.9753x over previous
//
#include <hip/hip_runtime.h>
#include <hip/hip_bf16.h>

typedef __attribute__((ext_vector_type(8))) short short8;
typedef __attribute__((ext_vector_type(4))) short shortx4;
typedef __attribute__((ext_vector_type(4))) float floatx4;

// N=128, C=64, T=256, V=25, S=3, RED=4, KER=25, PAD=12
#define NB   128
#define TT   256
#define TW   4
#define X_N  409600
#define X_C  6400

// workspace layout (float offsets)
#define WS_P     0        // 204800 floats
#define WS_GATE  204800   // 204800 floats
#define WS_B2    409600   // 64 floats
#define WS_AFB   409664   // 2560 ushorts (1280 floats)
#define WS_W2B   410944   // 12288 ushorts (6144 floats)

static __device__ __forceinline__ ushort f2b(float f) {
    union { __hip_bfloat16 h; ushort u; } c;
    c.h = __float2bfloat16(f);
    return c.u;
}
static __device__ __forceinline__ float b2f(ushort u) {
    union { ushort u; __hip_bfloat16 h; } c;
    c.u = u;
    return __bfloat162float(c.h);
}

// ---------------- prep: fold BN, build MFMA-fragment-packed weights ----------
__global__ __launch_bounds__(256) void prep_kernel(
    const float* __restrict__ A, const float* __restrict__ PA,
    const float* __restrict__ wd, const float* __restrict__ bd,
    const float* __restrict__ gamma, const float* __restrict__ beta,
    const float* __restrict__ mean, const float* __restrict__ var,
    float* __restrict__ bias2, ushort* __restrict__ Afb, ushort* __restrict__ W2b)
{
    __shared__ float norms[75];
    __shared__ float scs[64];
    int tid = threadIdx.x;
    if (tid < 75) {
        int s = tid / 25, w = tid - s * 25;
        float acc = 0.f;
        for (int i = 0; i < 25; ++i) {
            float v = PA[s * 625 + i * 25 + w];
            acc += v * v;
        }
        norms[tid] = sqrtf(acc) + 1e-4f;   // L2 over rows, per column
    }
    if (tid < 64) {
        float sc = gamma[tid] * rsqrtf(var[tid] + 1e-5f);
        scs[tid] = sc;
        float bsum = bd[tid] + bd[64 + tid] + bd[128 + tid];
        bias2[tid] = bsum * sc + beta[tid] - mean[tid] * sc;
    }
    __syncthreads();
    // Af B-fragments: B[k=v][n=(s,w)]; lane holds B[quad*8+j][lane&15], tile nt
    for (int i = tid; i < 2560; i += 256) {
        int j = i & 7; int lane = (i >> 3) & 63; int nt = i >> 9;
        int scol = nt * 16 + (lane & 15);
        int v = ((lane >> 4) & 3) * 8 + j;
        float val = 0.f;
        if (scol < 75 && v < 25) {
            int s = scol / 25, w = scol - s * 25;
            int idx = s * 625 + v * 25 + w;
            val = A[idx] + PA[idx] / norms[s * 25 + w];
        }
        Afb[i] = f2b(val);
    }
    // W2 A-fragments: A[m=o][k=s*64+c] (BN scale folded); [ot][kstep][lane][8]
    for (int i = tid; i < 12288; i += 256) {
        int j = i & 7; int lane = (i >> 3) & 63; int kq = i >> 9;
        int k = kq % 6; int ot = kq / 6;
        int o = ot * 16 + (lane & 15);
        int kk = k * 32 + ((lane >> 4) & 3) * 8 + j;
        int s = kk >> 6, c = kk & 63;
        W2b[i] = f2b(wd[s * 4096 + o * 64 + c] * scs[o]);
    }
}

// ---------------- main: double-MFMA einsum + BN + residual + ReLU + pool -----
// grid = 128 n x 64 t-tiles(TW=4), 256 threads (4 waves)
__global__ __launch_bounds__(256, 2) void main_kernel(
    const float* __restrict__ x, const ushort* __restrict__ Afb,
    const ushort* __restrict__ W2b, const float* __restrict__ bias2,
    float* __restrict__ yout, float* __restrict__ p)
{
    __shared__ ushort xs[4 * 64 * 36];   // x tile bf16 [t][c][v pad36], 18432 B
    __shared__ ushort zb[112 * 200];     // z bf16 [col=(t,w)][k=(s,c) pad200], 44800 B

    int blk = blockIdx.x;
    int n = blk >> 6, tb = blk & 63, t0 = tb * TW;
    int tid = threadIdx.x;
    int q = tid >> 6, lane = tid & 63, lm = lane & 15, quad = lane >> 4;

    // block-invariant fragments (L2-hot)
    short8 bfr[5];
    #pragma unroll
    for (int nt = 0; nt < 5; ++nt)
        bfr[nt] = *(const short8*)(Afb + (nt * 64 + lane) * 8);
    short8 wf[6];
    #pragma unroll
    for (int k = 0; k < 6; ++k)
        wf[k] = *(const short8*)(W2b + ((q * 6 + k) * 64 + lane) * 8);
    floatx4 bias = *(const floatx4*)(bias2 + q * 16 + quad * 4);

    // stage 0: x tile -> LDS bf16 (coalesced read, scalar cvt/write)
    const float* xn = x + (size_t)n * X_N + t0 * 25;
    for (int i = tid; i < 6400; i += 256) {
        int c = i / 100, r = i - c * 100;
        int t = r / 25, v = r - t * 25;
        xs[(t * 64 + c) * 36 + v] = f2b(xn[c * X_C + r]);
    }
    // zero the K-pad (v=25..31)
    for (int i = tid; i < 1792; i += 256) {
        int c = i / 28, rr = i - c * 28;
        int t = rr / 7, v = 25 + (rr - t * 7);
        xs[(t * 64 + c) * 36 + v] = 0;
    }
    __syncthreads();

    // stage 1: z[c][(s,w)] = sum_v x[c][v] Af[v][(s,w)]; wave q handles t=q
    {
        const int t = q;
        #pragma unroll
        for (int cm = 0; cm < 4; ++cm) {
            const ushort* ap = &xs[(t * 64 + cm * 16 + lm) * 36 + quad * 8];
            shortx4 a0 = *(const shortx4*)ap;
            shortx4 a1 = *(const shortx4*)(ap + 4);
            short8 av = __builtin_shufflevector(a0, a1, 0, 1, 2, 3, 4, 5, 6, 7);
            #pragma unroll
            for (int nt = 0; nt < 5; ++nt) {
                floatx4 d = __builtin_amdgcn_mfma_f32_16x16x32_bf16(
                    av, bfr[nt], (floatx4)(0.f), 0, 0, 0);
                int scol = nt * 16 + lm;
                if (scol < 75) {
                    int s = scol / 25, w = scol - s * 25;
                    int zcol = t * 25 + w;
                    int krow = s * 64 + cm * 16 + quad * 4;   // rows = c (consecutive)
                    shortx4 sv;
                    sv.x = (short)f2b(d.x); sv.y = (short)f2b(d.y);
                    sv.z = (short)f2b(d.z); sv.w = (short)f2b(d.w);
                    *(shortx4*)(&zb[zcol * 200 + krow]) = sv;
                }
            }
        }
    }
    __syncthreads();

    // stage 2: y[o][(t,w)] = sum_{s,c} W2[o][(s,c)] z[(s,c)][(t,w)]
    // wave q -> o-tile q; K = 192 = 6 steps of 32
    floatx4 acc[7];
    #pragma unroll
    for (int nt = 0; nt < 7; ++nt) acc[nt] = (floatx4)(0.f);
    #pragma unroll
    for (int k = 0; k < 6; ++k) {
        #pragma unroll
        for (int nt = 0; nt < 7; ++nt) {
            int col = nt * 16 + lm;
            short8 b = *(const short8*)(&zb[col * 200 + k * 32 + quad * 8]);
            acc[nt] = __builtin_amdgcn_mfma_f32_16x16x32_bf16(wf[k], b, acc[nt], 0, 0, 0);
        }
    }
    __syncthreads();   // all zb reads done; reuse as ypool

    float* ypool = (float*)zb;
    for (int i = tid; i < 1600; i += 256) ypool[i] = 0.f;
    __syncthreads();

    // epilogue: +bias +residual, ReLU, store, pool
    int o0 = q * 16 + quad * 4;
    #pragma unroll
    for (int nt = 0; nt < 7; ++nt) {
        int col = nt * 16 + lm;
        if (col < 100) {
            int t = col / 25, w = col - t * 25;
            size_t base = (size_t)n * X_N + (size_t)o0 * X_C + (size_t)(t0 + t) * 25 + w;
            #pragma unroll
            for (int r = 0; r < 4; ++r) {
                float res = b2f(xs[(t * 64 + o0 + r) * 36 + w]);
                float vv = acc[nt][r] + bias[r] + res;
                vv = fmaxf(vv, 0.f);
                yout[base + (size_t)r * X_C] = vv;
                atomicAdd(&ypool[(o0 + r) * 25 + w], vv);
            }
        }
    }
    __syncthreads();
    for (int i = tid; i < 1600; i += 256)
        atomicAdd(&p[(size_t)n * 1600 + i], ypool[i]);
}

// ---------------- SCE gate ----------------
__global__ __launch_bounds__(256) void sce_kernel(
    const float* __restrict__ p, const float* __restrict__ sws,
    const float* __restrict__ sbs, const float* __restrict__ swe,
    const float* __restrict__ sbe, float* __restrict__ gate)
{
    __shared__ float pm[1600];
    __shared__ float wss[6400];
    __shared__ float sq[100];
    int n = blockIdx.x, tid = threadIdx.x;
    for (int i = tid; i < 1600; i += 256) pm[i] = p[n * 1600 + i] * (1.f / 256.f);
    for (int i = tid; i < 6400; i += 256) wss[i] = sws[i];
    __syncthreads();
    if (tid < 100) {
        int r = tid / 25, w = tid - (tid / 25) * 25;
        float acc = sbs[r];
        for (int o = 0; o < 64; ++o) {
            const float* wr = &wss[(r * 64 + o) * 25];
            const float* pr = &pm[o * 25];
            int k0 = (w < 12) ? 12 - w : 0;
            int k1 = (w > 12) ? 37 - w : 25;
            for (int k = k0; k < k1; ++k) acc += pr[w + k - 12] * wr[k];
        }
        sq[tid] = fmaxf(acc, 0.f);
    }
    __syncthreads();
    for (int i = tid; i < 1600; i += 256) {
        int o = i / 25, w = i - (i / 25) * 25;
        float acc = sbe[o];
        #pragma unroll
        for (int r = 0; r < 4; ++r) acc += sq[r * 25 + w] * swe[o * 4 + r];
        gate[n * 1600 + i] = 1.f + 1.f / (1.f + __expf(-acc));
    }
}

// ---------------- final gated multiply (in-place on d_out) ----------------
__global__ __launch_bounds__(256) void gate_mul_kernel(
    float* __restrict__ y, const float* __restrict__ gate)
{
    unsigned int i = (blockIdx.x * 256u + threadIdx.x) * 4u;
    float4 v = *(float4*)(y + i);
    unsigned int i1 = i + 1, i2 = i + 2, i3 = i + 3;
    float g0 = gate[(i  / 6400u) * 25u + (i  % 25u)];
    float g1 = gate[(i1 / 6400u) * 25u + (i1 % 25u)];
    float g2 = gate[(i2 / 6400u) * 25u + (i2 % 25u)];
    float g3 = gate[(i3 / 6400u) * 25u + (i3 % 25u)];
    v.x *= g0; v.y *= g1; v.z *= g2; v.w *= g3;
    *(float4*)(y + i) = v;
}

extern "C" void kernel_launch(void* const* d_in, const int* in_sizes, int n_in,
                              void* d_out, int out_size, void* d_ws, size_t ws_size,
                              hipStream_t stream) {
    const float* x     = (const float*)d_in[0];
    const float* A     = (const float*)d_in[1];
    const float* PA    = (const float*)d_in[2];
    const float* wd    = (const float*)d_in[3];
    const float* bd    = (const float*)d_in[4];
    const float* gamma = (const float*)d_in[5];
    const float* beta  = (const float*)d_in[6];
    const float* mean  = (const float*)d_in[7];
    const float* var   = (const float*)d_in[8];
    const float* sws   = (const float*)d_in[9];
    const float* sbs   = (const float*)d_in[10];
    const float* swe   = (const float*)d_in[11];
    const float* sbe   = (const float*)d_in[12];

    float* out   = (float*)d_out;
    float* ws    = (float*)d_ws;
    float* p     = ws + WS_P;
    float* gate  = ws + WS_GATE;
    float* bias2 = ws + WS_B2;
    ushort* Afb  = (ushort*)(ws + WS_AFB);
    ushort* W2b  = (ushort*)(ws + WS_W2B);

    hipMemsetAsync(p, 0, 204800 * sizeof(float), stream);

    prep_kernel<<<1, 256, 0, stream>>>(A, PA, wd, bd, gamma, beta, mean, var,
                                       bias2, Afb, W2b);
    main_kernel<<<NB * (TT / TW), 256, 0, stream>>>(x, Afb, W2b, bias2, out, p);
    sce_kernel<<<NB, 256, 0, stream>>>(p, sws, sbs, swe, sbe, gate);
    gate_mul_kernel<<<out_size / (256 * 4), 256, 0, stream>>>(out, gate);
}

// Round 3
// 740.491 us; speedup vs baseline: 2.0977x; 1.0620x over previous
//
#include <hip/hip_runtime.h>
#include <hip/hip_bf16.h>

typedef __attribute__((ext_vector_type(8))) short short8;
typedef __attribute__((ext_vector_type(4))) short shortx4;
typedef __attribute__((ext_vector_type(4))) float floatx4;

// N=128, C=64, T=256, V=25, S=3, RED=4, KER=25, PAD=12
#define NB   128
#define TT   256
#define TW   4
#define X_N  409600
#define X_C  6400

// workspace layout (float offsets)
#define WS_GATE  0        // 204800 floats
#define WS_B2    204800   // 64 floats
#define WS_AFB   204864   // 2560 ushorts (1280 floats)
#define WS_W2B   206144   // 12288 ushorts (6144 floats)
#define WS_PART  212288   // path A: 8192*1600 floats partials; path B: p (204800 floats)

static __device__ __forceinline__ ushort f2b(float f) {
    union { __hip_bfloat16 h; ushort u; } c;
    c.h = __float2bfloat16(f);
    return c.u;
}
static __device__ __forceinline__ float b2f(ushort u) {
    union { ushort u; __hip_bfloat16 h; } c;
    c.u = u;
    return __bfloat162float(c.h);
}

// ---------------- prep: fold BN, build MFMA-fragment-packed weights ----------
__global__ __launch_bounds__(256) void prep_kernel(
    const float* __restrict__ A, const float* __restrict__ PA,
    const float* __restrict__ wd, const float* __restrict__ bd,
    const float* __restrict__ gamma, const float* __restrict__ beta,
    const float* __restrict__ mean, const float* __restrict__ var,
    float* __restrict__ bias2, ushort* __restrict__ Afb, ushort* __restrict__ W2b)
{
    __shared__ float norms[75];
    __shared__ float scs[64];
    int tid = threadIdx.x;
    int gid = blockIdx.x * 256 + tid;
    if (tid < 75) {
        int s = tid / 25, w = tid - s * 25;
        float acc = 0.f;
        for (int i = 0; i < 25; ++i) {
            float v = PA[s * 625 + i * 25 + w];
            acc += v * v;
        }
        norms[tid] = sqrtf(acc) + 1e-4f;   // L2 over rows, per column
    }
    if (tid < 64) {
        float sc = gamma[tid] * rsqrtf(var[tid] + 1e-5f);
        scs[tid] = sc;
        if (blockIdx.x == 0) {
            float bsum = bd[tid] + bd[64 + tid] + bd[128 + tid];
            bias2[tid] = bsum * sc + beta[tid] - mean[tid] * sc;
        }
    }
    __syncthreads();
    // Af B-fragments: B[k=v][n=(s,w)]; lane holds B[quad*8+j][lane&15], tile nt
    for (int i = gid; i < 2560; i += 4096) {
        int j = i & 7; int lane = (i >> 3) & 63; int nt = i >> 9;
        int scol = nt * 16 + (lane & 15);
        int v = ((lane >> 4) & 3) * 8 + j;
        float val = 0.f;
        if (scol < 75 && v < 25) {
            int s = scol / 25, w = scol - s * 25;
            int idx = s * 625 + v * 25 + w;
            val = A[idx] + PA[idx] / norms[s * 25 + w];
        }
        Afb[i] = f2b(val);
    }
    // W2 A-fragments: A[m=o][k=s*64+c] (BN scale folded); [ot][kstep][lane][8]
    for (int i = gid; i < 12288; i += 4096) {
        int j = i & 7; int lane = (i >> 3) & 63; int kq = i >> 9;
        int k = kq % 6; int ot = kq / 6;
        int o = ot * 16 + (lane & 15);
        int kk = k * 32 + ((lane >> 4) & 3) * 8 + j;
        int s = kk >> 6, c = kk & 63;
        W2b[i] = f2b(wd[s * 4096 + o * 64 + c] * scs[o]);
    }
}

// ---------------- main: double-MFMA einsum + BN + residual + ReLU + pool -----
// grid = 128 n x 64 t-tiles(TW=4), 512 threads (8 waves)
template<bool PART>
__global__ __launch_bounds__(512, 4) void main_kernel(
    const float* __restrict__ x, const ushort* __restrict__ Afb,
    const ushort* __restrict__ W2b, const float* __restrict__ bias2,
    float* __restrict__ yout, float* __restrict__ part)
{
    __shared__ ushort xs[4 * 64 * 36];   // x tile bf16 [t][c][v pad36], 18432 B
    __shared__ ushort zb[112 * 200];     // z bf16 [col][k pad200] 44800 B | ypf floats
    float* ypf = (float*)zb;             // 6400 floats [o][t*25+w]

    int blk = blockIdx.x;
    int n = blk >> 6, tb = blk & 63, t0 = tb * TW;
    int tid = threadIdx.x;
    int w8 = tid >> 6, lane = tid & 63, lm = lane & 15, quad = lane >> 4;
    int ot = w8 & 3, h = w8 >> 2;        // stage2: o-tile, col-half

    // block-invariant fragments (L2-hot)
    short8 bfr[5];
    #pragma unroll
    for (int nt = 0; nt < 5; ++nt)
        bfr[nt] = *(const short8*)(Afb + (nt * 64 + lane) * 8);
    short8 wf[6];
    #pragma unroll
    for (int k = 0; k < 6; ++k)
        wf[k] = *(const short8*)(W2b + ((ot * 6 + k) * 64 + lane) * 8);
    floatx4 bias = *(const floatx4*)(bias2 + ot * 16 + quad * 4);

    // stage 0: x tile -> LDS bf16
    const float* xn = x + (size_t)n * X_N + t0 * 25;
    for (int i = tid; i < 6400; i += 512) {
        int c = i / 100, r = i - c * 100;
        int t = r / 25, v = r - t * 25;
        xs[(t * 64 + c) * 36 + v] = f2b(xn[c * X_C + r]);
    }
    for (int i = tid; i < 1792; i += 512) {
        int c = i / 28, rr = i - c * 28;
        int t = rr / 7, v = 25 + (rr - t * 7);
        xs[(t * 64 + c) * 36 + v] = 0;
    }
    __syncthreads();

    // stage 1: z[c][(s,w)] = sum_v x[c][v] Af[v][(s,w)]
    // wave (t = w8&3, cm in {2h, 2h+1}): 10 MFMA each
    {
        const int t = w8 & 3;
        #pragma unroll
        for (int cj = 0; cj < 2; ++cj) {
            int cm = h * 2 + cj;
            const ushort* ap = &xs[(t * 64 + cm * 16 + lm) * 36 + quad * 8];
            shortx4 a0 = *(const shortx4*)ap;
            shortx4 a1 = *(const shortx4*)(ap + 4);
            short8 av = __builtin_shufflevector(a0, a1, 0, 1, 2, 3, 4, 5, 6, 7);
            #pragma unroll
            for (int nt = 0; nt < 5; ++nt) {
                floatx4 d = __builtin_amdgcn_mfma_f32_16x16x32_bf16(
                    av, bfr[nt], (floatx4)(0.f), 0, 0, 0);
                int scol = nt * 16 + lm;
                if (scol < 75) {
                    int s = scol / 25, w = scol - s * 25;
                    int zcol = t * 25 + w;
                    int krow = s * 64 + cm * 16 + quad * 4;
                    shortx4 sv;
                    sv.x = (short)f2b(d.x); sv.y = (short)f2b(d.y);
                    sv.z = (short)f2b(d.z); sv.w = (short)f2b(d.w);
                    *(shortx4*)(&zb[zcol * 200 + krow]) = sv;
                }
            }
        }
    }
    __syncthreads();

    // stage 2: y[o][(t,w)] = sum_{s,c} W2[o][(s,c)] z[(s,c)][(t,w)]
    // wave (ot, h): o-tile ot, col-tiles nt in [4h, 4h+4) ∩ [0,7)
    floatx4 acc[4];
    int nt0 = h * 4;
    #pragma unroll
    for (int j = 0; j < 4; ++j) acc[j] = bias;   // bias folded into init
    #pragma unroll
    for (int k = 0; k < 6; ++k) {
        #pragma unroll
        for (int j = 0; j < 4; ++j) {
            int nt = nt0 + j;
            if (nt < 7) {
                int col = nt * 16 + lm;
                short8 b = *(const short8*)(&zb[col * 200 + k * 32 + quad * 8]);
                acc[j] = __builtin_amdgcn_mfma_f32_16x16x32_bf16(wf[k], b, acc[j], 0, 0, 0);
            }
        }
    }
    __syncthreads();   // all zb reads done; reuse as ypf

    // scatter acc -> ypf[o][t*25+w]
    int o0 = ot * 16 + quad * 4;
    #pragma unroll
    for (int j = 0; j < 4; ++j) {
        int nt = nt0 + j;
        if (nt < 7) {
            int col = nt * 16 + lm;
            if (col < 100) {
                #pragma unroll
                for (int r = 0; r < 4; ++r)
                    ypf[(o0 + r) * 100 + col] = acc[j][r];
            }
        }
    }
    __syncthreads();

    // finalize: +residual, ReLU, coalesced store; keep for pool
    size_t ybase = (size_t)n * X_N + (size_t)tb * 100;
    for (int j = tid; j < 6400; j += 512) {
        int o = j / 100, rr = j - o * 100;
        int t = rr / 25, w = rr - t * 25;
        float v = ypf[j] + b2f(xs[(t * 64 + o) * 36 + w]);
        v = fmaxf(v, 0.f);
        yout[ybase + (size_t)o * X_C + rr] = v;
        if (PART) ypf[j] = v;
    }
    if (PART) {
        __syncthreads();
        for (int i = tid; i < 1600; i += 512) {
            int o = i / 25, w = i - o * 25;
            const float* yp = &ypf[o * 100 + w];
            part[(size_t)blk * 1600 + i] = yp[0] + yp[25] + yp[50] + yp[75];
        }
    }
}

// ---------------- path-B pool: p[n][o][w] = sum_t y ----------------
__global__ __launch_bounds__(256) void pool_kernel(
    const float* __restrict__ y, float* __restrict__ p)
{
    __shared__ float red[8][25];
    int no = blockIdx.x;            // n*64 + o
    int tid = threadIdx.x;
    if (tid < 200) {
        int tg = tid / 25, w = tid - tg * 25;
        const float* yp = y + (size_t)no * 6400 + w;
        float s = 0.f;
        for (int t = tg * 32; t < tg * 32 + 32; ++t) s += yp[t * 25];
        red[tg][w] = s;
    }
    __syncthreads();
    if (tid < 25) {
        float s = 0.f;
        #pragma unroll
        for (int g = 0; g < 8; ++g) s += red[g][tid];
        p[(size_t)no * 25 + tid] = s;
    }
}

// ---------------- SCE gate ----------------
template<bool PART>
__global__ __launch_bounds__(256) void sce_kernel(
    const float* __restrict__ pp, const float* __restrict__ sws,
    const float* __restrict__ sbs, const float* __restrict__ swe,
    const float* __restrict__ sbe, float* __restrict__ gate)
{
    __shared__ float pm[1600];
    __shared__ float wss[6400];
    __shared__ float sq[100];
    int n = blockIdx.x, tid = threadIdx.x;
    if (PART) {
        for (int i = tid; i < 1600; i += 256) {
            const float* q = pp + (size_t)n * 64 * 1600 + i;
            float s = 0.f;
            for (int tb = 0; tb < 64; ++tb) s += q[(size_t)tb * 1600];
            pm[i] = s * (1.f / 256.f);
        }
    } else {
        for (int i = tid; i < 1600; i += 256)
            pm[i] = pp[(size_t)n * 1600 + i] * (1.f / 256.f);
    }
    for (int i = tid; i < 6400; i += 256) wss[i] = sws[i];
    __syncthreads();
    if (tid < 100) {
        int r = tid / 25, w = tid - (tid / 25) * 25;
        float acc = sbs[r];
        for (int o = 0; o < 64; ++o) {
            const float* wr = &wss[(r * 64 + o) * 25];
            const float* pr = &pm[o * 25];
            int k0 = (w < 12) ? 12 - w : 0;
            int k1 = (w > 12) ? 37 - w : 25;
            for (int k = k0; k < k1; ++k) acc += pr[w + k - 12] * wr[k];
        }
        sq[tid] = fmaxf(acc, 0.f);
    }
    __syncthreads();
    for (int i = tid; i < 1600; i += 256) {
        int o = i / 25, w = i - (i / 25) * 25;
        float acc = sbe[o];
        #pragma unroll
        for (int r = 0; r < 4; ++r) acc += sq[r * 25 + w] * swe[o * 4 + r];
        gate[(size_t)n * 1600 + i] = 1.f + 1.f / (1.f + __expf(-acc));
    }
}

// ---------------- final gated multiply (in-place on d_out) ----------------
__global__ __launch_bounds__(256) void gate_mul_kernel(
    float* __restrict__ y, const float* __restrict__ gate)
{
    unsigned int i = (blockIdx.x * 256u + threadIdx.x) * 4u;
    float4 v = *(float4*)(y + i);
    unsigned int i1 = i + 1, i2 = i + 2, i3 = i + 3;
    float g0 = gate[(i  / 6400u) * 25u + (i  % 25u)];
    float g1 = gate[(i1 / 6400u) * 25u + (i1 % 25u)];
    float g2 = gate[(i2 / 6400u) * 25u + (i2 % 25u)];
    float g3 = gate[(i3 / 6400u) * 25u + (i3 % 25u)];
    v.x *= g0; v.y *= g1; v.z *= g2; v.w *= g3;
    *(float4*)(y + i) = v;
}

extern "C" void kernel_launch(void* const* d_in, const int* in_sizes, int n_in,
                              void* d_out, int out_size, void* d_ws, size_t ws_size,
                              hipStream_t stream) {
    const float* x     = (const float*)d_in[0];
    const float* A     = (const float*)d_in[1];
    const float* PA    = (const float*)d_in[2];
    const float* wd    = (const float*)d_in[3];
    const float* bd    = (const float*)d_in[4];
    const float* gamma = (const float*)d_in[5];
    const float* beta  = (const float*)d_in[6];
    const float* mean  = (const float*)d_in[7];
    const float* var   = (const float*)d_in[8];
    const float* sws   = (const float*)d_in[9];
    const float* sbs   = (const float*)d_in[10];
    const float* swe   = (const float*)d_in[11];
    const float* sbe   = (const float*)d_in[12];

    float* out   = (float*)d_out;
    float* ws    = (float*)d_ws;
    float* gate  = ws + WS_GATE;
    float* bias2 = ws + WS_B2;
    ushort* Afb  = (ushort*)(ws + WS_AFB);
    ushort* W2b  = (ushort*)(ws + WS_W2B);
    float* part  = ws + WS_PART;

    // partials need 8192*1600 floats beyond WS_PART
    bool useA = ws_size >= ((size_t)WS_PART + (size_t)8192 * 1600) * 4;

    prep_kernel<<<16, 256, 0, stream>>>(A, PA, wd, bd, gamma, beta, mean, var,
                                        bias2, Afb, W2b);
    if (useA) {
        main_kernel<true><<<NB * (TT / TW), 512, 0, stream>>>(x, Afb, W2b, bias2, out, part);
        sce_kernel<true><<<NB, 256, 0, stream>>>(part, sws, sbs, swe, sbe, gate);
    } else {
        main_kernel<false><<<NB * (TT / TW), 512, 0, stream>>>(x, Afb, W2b, bias2, out, part);
        pool_kernel<<<NB * 64, 256, 0, stream>>>(out, part);
        sce_kernel<false><<<NB, 256, 0, stream>>>(part, sws, sbs, swe, sbe, gate);
    }
    gate_mul_kernel<<<out_size / (256 * 4), 256, 0, stream>>>(out, gate);
}